// Round 5
// baseline (1308.664 us; speedup 1.0000x reference)
//
#include <hip/hip_runtime.h>

using f32x4  = __attribute__((ext_vector_type(4))) float;
using short8 = __attribute__((ext_vector_type(8))) short;

__device__ inline short f2bf(float x) {
    union { float f; unsigned u; } v; v.f = x;
    unsigned r = v.u + 0x7fffu + ((v.u >> 16) & 1u);   // RNE
    return (short)(r >> 16);
}

__device__ inline short8 pack8(float4 a, float4 b) {
    short8 r;
    r[0] = f2bf(a.x); r[1] = f2bf(a.y); r[2] = f2bf(a.z); r[3] = f2bf(a.w);
    r[4] = f2bf(b.x); r[5] = f2bf(b.y); r[6] = f2bf(b.z); r[7] = f2bf(b.w);
    return r;
}

// ---------------------------------------------------------------------------
// Weight prep: f32 -> bf16 transposed. Layer-1 K permuted:
// k 0..63 = h_src rows; 64..127 = h_dst rows; 128..143 = ea (orig 129..144);
// 144 = dist2 (orig 128); 145..159 = zero. WnT[64][128] for node MLP.
// ---------------------------------------------------------------------------
__global__ __launch_bounds__(256) void convert_weights(
    const float* __restrict__ We1, const float* __restrict__ We2,
    const float* __restrict__ Wc1, const float* __restrict__ Wn,
    short* __restrict__ W1T, short* __restrict__ W2T,
    short* __restrict__ Wc1T, short* __restrict__ WnT)
{
    const int i = blockIdx.x * 256 + threadIdx.x;
    if (i < 64 * 160) {
        const int n = i / 160, k = i % 160;
        float v = 0.0f;
        if (k < 128)       v = We1[k * 64 + n];
        else if (k < 144)  v = We1[(129 + k - 128) * 64 + n];
        else if (k == 144) v = We1[128 * 64 + n];
        W1T[i] = f2bf(v);
    }
    if (i < 64 * 128) {
        const int n = i / 128, k = i % 128;
        WnT[i] = f2bf(Wn[k * 64 + n]);
    }
    if (i < 64 * 64) {
        const int n = i / 64, k = i % 64;
        W2T[i]  = f2bf(We2[k * 64 + n]);
        Wc1T[i] = f2bf(Wc1[k * 64 + n]);
    }
}

__global__ __launch_bounds__(256) void convert_h(
    const float* __restrict__ h, short* __restrict__ hb, int n8)
{
    const int i = blockIdx.x * 256 + threadIdx.x;
    if (i < n8) {
        const float4* h4 = reinterpret_cast<const float4*>(h);
        reinterpret_cast<short8*>(hb)[i] = pack8(h4[2 * i], h4[2 * i + 1]);
    }
}

// ---------------------------------------------------------------------------
// CSR build: count -> scan -> fill (int atomics only).
// ---------------------------------------------------------------------------
__global__ __launch_bounds__(256) void count_kernel(
    const int* __restrict__ ei, int* __restrict__ cnt, int E)
{
    const int e = blockIdx.x * 256 + threadIdx.x;
    if (e < E) atomicAdd(&cnt[ei[E + e]], 1);
}

__global__ __launch_bounds__(1024) void scan_kernel(
    const int* __restrict__ cnt, int* __restrict__ start, int N)
{
    __shared__ int part[1024];
    const int tid = threadIdx.x;
    const int per = (N + 1023) >> 10;
    const int lo = tid * per;
    const int hi = min(lo + per, N);
    int s = 0;
    for (int i = lo; i < hi; ++i) s += cnt[i];
    part[tid] = s;
    __syncthreads();
    for (int off = 1; off < 1024; off <<= 1) {
        int v = (tid >= off) ? part[tid - off] : 0;
        __syncthreads();
        part[tid] += v;
        __syncthreads();
    }
    int off0 = (tid == 0) ? 0 : part[tid - 1];
    for (int i = lo; i < hi; ++i) { start[i] = off0; off0 += cnt[i]; }
    if (tid == 1023) start[N] = part[1023];
}

__global__ __launch_bounds__(256) void fill_kernel(
    const int* __restrict__ ei, const int* __restrict__ start,
    int* __restrict__ cursor, int* __restrict__ eidbuf, int E)
{
    const int e = blockIdx.x * 256 + threadIdx.x;
    if (e < E) {
        const int d = ei[E + e];
        const int slot = start[d] + atomicAdd(&cursor[d], 1);
        eidbuf[slot] = e;
    }
}

// ---------------------------------------------------------------------------
// Gather-side edge pipeline: wave per dst-node, chunks of 16 edges through
// the 3-GEMM MFMA pipeline; agg/trans accumulated in registers, written once
// per node. ZERO float atomics. No __syncthreads.
// mfma_f32_16x16x32_bf16; D: col=lane&15, row=(lane>>4)*4+reg  [m89].
// ---------------------------------------------------------------------------
__global__ __launch_bounds__(256) void egnn_edge_gather(
    const short* __restrict__ hb, const float* __restrict__ pos,
    const int* __restrict__ ei, const float* __restrict__ ea,
    const short* __restrict__ W1T, const short* __restrict__ W2T,
    const short* __restrict__ Wc1T,
    const float* __restrict__ be1, const float* __restrict__ be2,
    const float* __restrict__ bc1, const float* __restrict__ bc2,
    const float* __restrict__ Wc2,
    const int* __restrict__ start, const int* __restrict__ eidbuf,
    short* __restrict__ aggb, float* __restrict__ dpos, int N, int E)
{
    __shared__ short M[4][16][72];      // wave-private ping-pong
    __shared__ float sdir[4][3][16];

    const int tid  = threadIdx.x;
    const int lane = tid & 63;
    const int wave = tid >> 6;
    const int r16  = lane & 15;
    const int kg   = lane >> 4;
    const int n    = blockIdx.x * 4 + wave;   // wave-uniform
    if (n >= N) return;

    const int s0 = start[n];
    const int s1 = start[n + 1];

    // node-common data (identical across chunks)
    const short8* hd = reinterpret_cast<const short8*>(hb + (size_t)n * 64);
    const short8 hd0 = hd[kg];
    const short8 hd1 = hd[4 + kg];
    const float pdx = pos[3 * n + 0], pdy = pos[3 * n + 1], pdz = pos[3 * n + 2];

    float b1v[4], b2v[4], b3v[4], w2v[4];
    #pragma unroll
    for (int nt = 0; nt < 4; ++nt) {
        b1v[nt] = be1[r16 + nt * 16];
        b2v[nt] = be2[r16 + nt * 16];
        b3v[nt] = bc1[r16 + nt * 16];
        w2v[nt] = Wc2[r16 + nt * 16];
    }
    const float bc2v = bc2[0];

    float cs0 = 0.0f, cs1 = 0.0f, cs2 = 0.0f, cs3 = 0.0f;  // agg col sums
    float t0 = 0.0f, t1 = 0.0f, t2 = 0.0f;                  // trans sums

    for (int c0 = s0; c0 < s1; c0 += 16) {
        // ---- this lane's edge (row r16 of the tile) ----
        const int slot = min(c0 + r16, s1 - 1);
        const int eid  = eidbuf[slot];
        const int src  = ei[eid];

        const float dx = pdx - pos[3 * src + 0];
        const float dy = pdy - pos[3 * src + 1];
        const float dz = pdz - pos[3 * src + 2];
        const float d2 = fminf(dx * dx + dy * dy + dz * dz, 1000.0f);
        const float inv = 1.0f / sqrtf(d2 + 1e-8f);
        if (kg == 0) {
            sdir[wave][0][r16] = dx * inv;
            sdir[wave][1][r16] = dy * inv;
            sdir[wave][2][r16] = dz * inv;
        }

        // ---- A fragments ----
        const short8* hs = reinterpret_cast<const short8*>(hb + (size_t)src * 64);
        const short8 a0 = hs[kg];
        const short8 a1 = hs[4 + kg];
        short8 a4 = {0, 0, 0, 0, 0, 0, 0, 0};
        if (kg < 2) {
            const float4* eap = reinterpret_cast<const float4*>(
                ea + (size_t)eid * 16 + kg * 8);
            a4 = pack8(eap[0], eap[1]);
        } else if (kg == 2) {
            a4[0] = f2bf(d2);
        }

        // ---- GEMM1: [16,160] @ [160,64] ----
        f32x4 acc1[4];
        #pragma unroll
        for (int nt = 0; nt < 4; ++nt)
            acc1[nt] = {b1v[nt], b1v[nt], b1v[nt], b1v[nt]};
        #pragma unroll
        for (int nt = 0; nt < 4; ++nt) {
            const short* wr = W1T + (r16 + nt * 16) * 160 + kg * 8;
            acc1[nt] = __builtin_amdgcn_mfma_f32_16x16x32_bf16(
                a0, *reinterpret_cast<const short8*>(wr), acc1[nt], 0, 0, 0);
            acc1[nt] = __builtin_amdgcn_mfma_f32_16x16x32_bf16(
                a1, *reinterpret_cast<const short8*>(wr + 32), acc1[nt], 0, 0, 0);
            acc1[nt] = __builtin_amdgcn_mfma_f32_16x16x32_bf16(
                hd0, *reinterpret_cast<const short8*>(wr + 64), acc1[nt], 0, 0, 0);
            acc1[nt] = __builtin_amdgcn_mfma_f32_16x16x32_bf16(
                hd1, *reinterpret_cast<const short8*>(wr + 96), acc1[nt], 0, 0, 0);
            acc1[nt] = __builtin_amdgcn_mfma_f32_16x16x32_bf16(
                a4, *reinterpret_cast<const short8*>(wr + 128), acc1[nt], 0, 0, 0);
        }
        #pragma unroll
        for (int nt = 0; nt < 4; ++nt)
            #pragma unroll
            for (int rg = 0; rg < 4; ++rg)
                M[wave][kg * 4 + rg][r16 + nt * 16] = f2bf(fmaxf(acc1[nt][rg], 0.0f));

        // ---- GEMM2 (f32 acc kept for agg) ----
        const short8 a5 = *reinterpret_cast<const short8*>(&M[wave][r16][kg * 8]);
        const short8 a6 = *reinterpret_cast<const short8*>(&M[wave][r16][32 + kg * 8]);
        f32x4 acc2[4];
        #pragma unroll
        for (int nt = 0; nt < 4; ++nt)
            acc2[nt] = {b2v[nt], b2v[nt], b2v[nt], b2v[nt]};
        #pragma unroll
        for (int nt = 0; nt < 4; ++nt) {
            const short* wr = W2T + (r16 + nt * 16) * 64 + kg * 8;
            acc2[nt] = __builtin_amdgcn_mfma_f32_16x16x32_bf16(
                a5, *reinterpret_cast<const short8*>(wr), acc2[nt], 0, 0, 0);
            acc2[nt] = __builtin_amdgcn_mfma_f32_16x16x32_bf16(
                a6, *reinterpret_cast<const short8*>(wr + 32), acc2[nt], 0, 0, 0);
        }
        #pragma unroll
        for (int nt = 0; nt < 4; ++nt)
            #pragma unroll
            for (int rg = 0; rg < 4; ++rg) {
                const float v = fmaxf(acc2[nt][rg], 0.0f);
                acc2[nt][rg] = v;
                M[wave][kg * 4 + rg][r16 + nt * 16] = f2bf(v);
            }

        // ---- accumulate agg over valid rows ----
        #pragma unroll
        for (int rg = 0; rg < 4; ++rg) {
            if (c0 + kg * 4 + rg < s1) {
                cs0 += acc2[0][rg]; cs1 += acc2[1][rg];
                cs2 += acc2[2][rg]; cs3 += acc2[3][rg];
            }
        }

        // ---- GEMM3 (coord MLP layer 1) ----
        const short8 a7 = *reinterpret_cast<const short8*>(&M[wave][r16][kg * 8]);
        const short8 a8 = *reinterpret_cast<const short8*>(&M[wave][r16][32 + kg * 8]);
        f32x4 acc3[4];
        #pragma unroll
        for (int nt = 0; nt < 4; ++nt)
            acc3[nt] = {b3v[nt], b3v[nt], b3v[nt], b3v[nt]};
        #pragma unroll
        for (int nt = 0; nt < 4; ++nt) {
            const short* wr = Wc1T + (r16 + nt * 16) * 64 + kg * 8;
            acc3[nt] = __builtin_amdgcn_mfma_f32_16x16x32_bf16(
                a7, *reinterpret_cast<const short8*>(wr), acc3[nt], 0, 0, 0);
            acc3[nt] = __builtin_amdgcn_mfma_f32_16x16x32_bf16(
                a8, *reinterpret_cast<const short8*>(wr + 32), acc3[nt], 0, 0, 0);
        }

        // ---- coef per row, trans accumulate ----
        float prt[4] = {0.0f, 0.0f, 0.0f, 0.0f};
        #pragma unroll
        for (int nt = 0; nt < 4; ++nt)
            #pragma unroll
            for (int rg = 0; rg < 4; ++rg)
                prt[rg] += fmaxf(acc3[nt][rg], 0.0f) * w2v[nt];
        #pragma unroll
        for (int off = 1; off < 16; off <<= 1)
            #pragma unroll
            for (int rg = 0; rg < 4; ++rg)
                prt[rg] += __shfl_xor(prt[rg], off);

        #pragma unroll
        for (int rg = 0; rg < 4; ++rg) {
            const int row = kg * 4 + rg;
            if (c0 + row < s1) {
                const float cf = tanhf(prt[rg] + bc2v) * 0.1f;
                t0 += sdir[wave][0][row] * cf;
                t1 += sdir[wave][1][row] * cf;
                t2 += sdir[wave][2][row] * cf;
            }
        }
    }

    // ---- cross-kg reduction (bits 4,5 of lane) ----
    #pragma unroll
    for (int off = 16; off <= 32; off <<= 1) {
        cs0 += __shfl_xor(cs0, off); cs1 += __shfl_xor(cs1, off);
        cs2 += __shfl_xor(cs2, off); cs3 += __shfl_xor(cs3, off);
        t0  += __shfl_xor(t0,  off); t1  += __shfl_xor(t1,  off);
        t2  += __shfl_xor(t2,  off);
    }

    const float myv = (kg == 0) ? cs0 : (kg == 1) ? cs1 : (kg == 2) ? cs2 : cs3;
    aggb[(size_t)n * 64 + kg * 16 + r16] = f2bf(myv);
    if (lane < 3)
        dpos[3 * n + lane] = (lane == 0) ? t0 : (lane == 1) ? t1 : t2;
}

// ---------------------------------------------------------------------------
// Node MLP + residual + LayerNorm, MFMA version. 64 nodes/block, 4 waves.
// ---------------------------------------------------------------------------
__global__ __launch_bounds__(256) void egnn_node_mfma(
    const float* __restrict__ h, const short* __restrict__ hb,
    const short* __restrict__ aggb, const float* __restrict__ pos,
    const float* __restrict__ dpos, const short* __restrict__ WnT,
    const float* __restrict__ bn, const float* __restrict__ lng,
    const float* __restrict__ lnb,
    float* __restrict__ h_out, float* __restrict__ pos_out, int N)
{
    __shared__ short As[64][136];   // cols 0..64 = h (bf16), 64..128 = agg
    const int tid = threadIdx.x;
    const int n0  = blockIdx.x * 64;

    if (tid < 64) {
        const int n = n0 + tid;
        if (n < N) {
            #pragma unroll
            for (int c = 0; c < 3; ++c)
                pos_out[(size_t)3 * n + c] = pos[(size_t)3 * n + c] + dpos[(size_t)3 * n + c];
        }
    }

    {
        const int row = tid >> 2, part = tid & 3;
        const int n = n0 + row;
        if (n < N) {
            const short* sp = (part < 2) ? (hb + (size_t)n * 64 + (part & 1) * 32)
                                         : (aggb + (size_t)n * 64 + (part & 1) * 32);
            #pragma unroll
            for (int q = 0; q < 4; ++q)
                *reinterpret_cast<short8*>(&As[row][part * 32 + q * 8]) =
                    *reinterpret_cast<const short8*>(sp + q * 8);
        }
    }
    __syncthreads();

    const int lane = tid & 63;
    const int wave = tid >> 6;
    const int r16  = lane & 15;
    const int kg   = lane >> 4;
    const int mrow = wave * 16 + r16;

    f32x4 acc[4];
    #pragma unroll
    for (int nt = 0; nt < 4; ++nt) {
        const float b = bn[r16 + nt * 16];
        acc[nt] = {b, b, b, b};
    }
    #pragma unroll
    for (int kt = 0; kt < 4; ++kt) {
        short8 a = *reinterpret_cast<const short8*>(&As[mrow][kt * 32 + kg * 8]);
        #pragma unroll
        for (int nt = 0; nt < 4; ++nt) {
            short8 b = *reinterpret_cast<const short8*>(
                &WnT[(r16 + nt * 16) * 128 + kt * 32 + kg * 8]);
            acc[nt] = __builtin_amdgcn_mfma_f32_16x16x32_bf16(a, b, acc[nt], 0, 0, 0);
        }
    }

    float xv[4][4];
    #pragma unroll
    for (int rg = 0; rg < 4; ++rg) {
        const int n = n0 + wave * 16 + kg * 4 + rg;
        const bool ok = n < N;
        #pragma unroll
        for (int nt = 0; nt < 4; ++nt)
            xv[nt][rg] = (ok ? h[(size_t)n * 64 + r16 + nt * 16] : 0.0f)
                         + fmaxf(acc[nt][rg], 0.0f);
    }

    float g[4], bb[4];
    #pragma unroll
    for (int nt = 0; nt < 4; ++nt) { g[nt] = lng[r16 + nt * 16]; bb[nt] = lnb[r16 + nt * 16]; }

    #pragma unroll
    for (int rg = 0; rg < 4; ++rg) {
        float s = xv[0][rg] + xv[1][rg] + xv[2][rg] + xv[3][rg];
        #pragma unroll
        for (int off = 1; off < 16; off <<= 1) s += __shfl_xor(s, off);
        const float mu = s * 0.015625f;
        float q = 0.0f;
        #pragma unroll
        for (int nt = 0; nt < 4; ++nt) { const float d = xv[nt][rg] - mu; q += d * d; }
        #pragma unroll
        for (int off = 1; off < 16; off <<= 1) q += __shfl_xor(q, off);
        const float inv = rsqrtf(q * 0.015625f + 1e-5f);
        const int n = n0 + wave * 16 + kg * 4 + rg;
        if (n < N) {
            #pragma unroll
            for (int nt = 0; nt < 4; ++nt)
                h_out[(size_t)n * 64 + r16 + nt * 16] =
                    (xv[nt][rg] - mu) * inv * g[nt] + bb[nt];
        }
    }
}

extern "C" void kernel_launch(void* const* d_in, const int* in_sizes, int n_in,
                              void* d_out, int out_size, void* d_ws, size_t ws_size,
                              hipStream_t stream)
{
    const float* h   = (const float*)d_in[0];
    const float* pos = (const float*)d_in[1];
    const int*   ei  = (const int*)d_in[2];
    const float* ea  = (const float*)d_in[3];
    const float* We1 = (const float*)d_in[4];
    const float* be1 = (const float*)d_in[5];
    const float* We2 = (const float*)d_in[6];
    const float* be2 = (const float*)d_in[7];
    const float* Wc1 = (const float*)d_in[8];
    const float* bc1 = (const float*)d_in[9];
    const float* Wc2 = (const float*)d_in[10];
    const float* bc2 = (const float*)d_in[11];
    const float* Wn  = (const float*)d_in[12];
    const float* bn  = (const float*)d_in[13];
    const float* lng = (const float*)d_in[14];
    const float* lnb = (const float*)d_in[15];

    const int N = in_sizes[0] / 64;
    const int E = in_sizes[2] / 2;

    // workspace layout (16B-aligned segments)
    short* aggb  = (short*)d_ws;                        // [N,64] bf16
    short* hbuf  = aggb + (size_t)N * 64;               // [N,64] bf16
    short* W1T   = hbuf + (size_t)N * 64;               // [64,160]
    short* W2T   = W1T + 64 * 160;                      // [64,64]
    short* Wc1T  = W2T + 64 * 64;                       // [64,64]
    short* WnT   = Wc1T + 64 * 64;                      // [64,128]
    float* dpos  = (float*)(WnT + 64 * 128);            // [N,3] f32
    int*   startp = (int*)(dpos + (size_t)N * 3);       // [N+1]
    int*   cnt    = startp + (N + 1);                   // [N]
    int*   cursor = cnt + N;                            // [N]
    int*   eidbuf = cursor + N;                         // [E]

    hipMemsetAsync(cnt, 0, (size_t)2 * N * sizeof(int), stream);  // cnt+cursor
    convert_weights<<<40, 256, 0, stream>>>(We1, We2, Wc1, Wn, W1T, W2T, Wc1T, WnT);
    convert_h<<<(N * 64 / 8 + 255) / 256, 256, 0, stream>>>(h, hbuf, N * 64 / 8);
    count_kernel<<<(E + 255) / 256, 256, 0, stream>>>(ei, cnt, E);
    scan_kernel<<<1, 1024, 0, stream>>>(cnt, startp, N);
    fill_kernel<<<(E + 255) / 256, 256, 0, stream>>>(ei, startp, cursor, eidbuf, E);

    float* h_out   = (float*)d_out;
    float* pos_out = h_out + (size_t)N * 64;

    egnn_edge_gather<<<(N + 3) / 4, 256, 0, stream>>>(
        hbuf, pos, ei, ea, W1T, W2T, Wc1T, be1, be2, bc1, bc2, Wc2,
        startp, eidbuf, aggb, dpos, N, E);
    egnn_node_mfma<<<(N + 63) / 64, 256, 0, stream>>>(
        h, hbuf, aggb, pos, dpos, WnT, bn, lng, lnb, h_out, pos_out, N);
}

// Round 6
// 739.278 us; speedup vs baseline: 1.7702x; 1.7702x over previous
//
#include <hip/hip_runtime.h>

using f32x4  = __attribute__((ext_vector_type(4))) float;
using short8 = __attribute__((ext_vector_type(8))) short;

__device__ inline short f2bf(float x) {
    union { float f; unsigned u; } v; v.f = x;
    unsigned r = v.u + 0x7fffu + ((v.u >> 16) & 1u);   // RNE
    return (short)(r >> 16);
}

__device__ inline short8 pack8(float4 a, float4 b) {
    short8 r;
    r[0] = f2bf(a.x); r[1] = f2bf(a.y); r[2] = f2bf(a.z); r[3] = f2bf(a.w);
    r[4] = f2bf(b.x); r[5] = f2bf(b.y); r[6] = f2bf(b.z); r[7] = f2bf(b.w);
    return r;
}

__device__ inline void atomic_pk_add_bf16(short* addr, unsigned pk) {
    asm volatile("global_atomic_pk_add_bf16 %0, %1, off"
                 :: "v"(addr), "v"(pk) : "memory");
}

// ---------------------------------------------------------------------------
// Weight prep: f32 -> bf16 transposed. Layer-1 K permuted:
// k 0..63 = h_src rows; 64..127 = h_dst rows; 128..143 = ea (orig 129..144);
// 144 = dist2 (orig 128); 145..159 = zero. WnT[64][128] for node MLP.
// ---------------------------------------------------------------------------
__global__ __launch_bounds__(256) void convert_weights(
    const float* __restrict__ We1, const float* __restrict__ We2,
    const float* __restrict__ Wc1, const float* __restrict__ Wn,
    short* __restrict__ W1T, short* __restrict__ W2T,
    short* __restrict__ Wc1T, short* __restrict__ WnT)
{
    const int i = blockIdx.x * 256 + threadIdx.x;
    if (i < 64 * 160) {
        const int n = i / 160, k = i % 160;
        float v = 0.0f;
        if (k < 128)       v = We1[k * 64 + n];
        else if (k < 144)  v = We1[(129 + k - 128) * 64 + n];
        else if (k == 144) v = We1[128 * 64 + n];
        W1T[i] = f2bf(v);
    }
    if (i < 64 * 128) {
        const int n = i / 128, k = i % 128;
        WnT[i] = f2bf(Wn[k * 64 + n]);
    }
    if (i < 64 * 64) {
        const int n = i / 64, k = i % 64;
        W2T[i]  = f2bf(We2[k * 64 + n]);
        Wc1T[i] = f2bf(Wc1[k * 64 + n]);
    }
}

__global__ __launch_bounds__(256) void convert_h(
    const float* __restrict__ h, short* __restrict__ hb, int n8)
{
    const int i = blockIdx.x * 256 + threadIdx.x;
    if (i < n8) {
        const float4* h4 = reinterpret_cast<const float4*>(h);
        reinterpret_cast<short8*>(hb)[i] = pack8(h4[2 * i], h4[2 * i + 1]);
    }
}

// ---------------------------------------------------------------------------
// CSR build: count -> scan -> fill (int atomics only). eidbuf = edge ids
// sorted (grouped) by dst.
// ---------------------------------------------------------------------------
__global__ __launch_bounds__(256) void count_kernel(
    const int* __restrict__ ei, int* __restrict__ cnt, int E)
{
    const int e = blockIdx.x * 256 + threadIdx.x;
    if (e < E) atomicAdd(&cnt[ei[E + e]], 1);
}

__global__ __launch_bounds__(1024) void scan_kernel(
    const int* __restrict__ cnt, int* __restrict__ start, int N)
{
    __shared__ int part[1024];
    const int tid = threadIdx.x;
    const int per = (N + 1023) >> 10;
    const int lo = tid * per;
    const int hi = min(lo + per, N);
    int s = 0;
    for (int i = lo; i < hi; ++i) s += cnt[i];
    part[tid] = s;
    __syncthreads();
    for (int off = 1; off < 1024; off <<= 1) {
        int v = (tid >= off) ? part[tid - off] : 0;
        __syncthreads();
        part[tid] += v;
        __syncthreads();
    }
    int off0 = (tid == 0) ? 0 : part[tid - 1];
    for (int i = lo; i < hi; ++i) { start[i] = off0; off0 += cnt[i]; }
    if (tid == 1023) start[N] = part[1023];
}

__global__ __launch_bounds__(256) void fill_kernel(
    const int* __restrict__ ei, const int* __restrict__ start,
    int* __restrict__ cursor, int* __restrict__ eidbuf, int E)
{
    const int e = blockIdx.x * 256 + threadIdx.x;
    if (e < E) {
        const int d = ei[E + e];
        const int slot = start[d] + atomicAdd(&cursor[d], 1);
        eidbuf[slot] = e;
    }
}

// ---------------------------------------------------------------------------
// Edge pipeline over dst-SORTED slots: 64 slots/block, 4 independent waves
// (16 slots each), no __syncthreads. Equal-dst rows are contiguous runs in
// each wave tile -> segmented (run) reduction, ONE atomic batch per run
// (~8x fewer atomics than per-edge scatter). Lean registers: geometry and
// run logic in regs, only M ping-pong in LDS.
// mfma_f32_16x16x32_bf16; D: col=lane&15, row=(lane>>4)*4+reg  [m89].
// ---------------------------------------------------------------------------
__global__ __launch_bounds__(256, 6) void egnn_edge_sorted(
    const short* __restrict__ hb, const float* __restrict__ pos,
    const int* __restrict__ ei, const float* __restrict__ ea,
    const short* __restrict__ W1T, const short* __restrict__ W2T,
    const short* __restrict__ Wc1T,
    const float* __restrict__ be1, const float* __restrict__ be2,
    const float* __restrict__ bc1, const float* __restrict__ bc2,
    const float* __restrict__ Wc2, const int* __restrict__ eidbuf,
    short* __restrict__ aggb, float* __restrict__ dpos, int E)
{
    __shared__ short M[4][16][72];      // 9216 B, wave-private ping-pong

    const int tid  = threadIdx.x;
    const int lane = tid & 63;
    const int wave = tid >> 6;
    const int r16  = lane & 15;
    const int kg   = lane >> 4;

    const int slot  = blockIdx.x * 64 + wave * 16 + r16;
    const bool vrow = slot < E;
    const int slotc = min(slot, E - 1);
    const int eid   = eidbuf[slotc];
    const int src   = ei[eid];
    const int dst   = ei[E + eid];
    const int dkey  = vrow ? dst : -1;     // run key (-1 rows never emitted)

    // ---- geometry (per own row, kept in regs) ----
    float dx = pos[3 * dst + 0] - pos[3 * src + 0];
    float dy = pos[3 * dst + 1] - pos[3 * src + 1];
    float dz = pos[3 * dst + 2] - pos[3 * src + 2];
    const float d2 = fminf(dx * dx + dy * dy + dz * dz, 1000.0f);
    const float inv = 1.0f / sqrtf(d2 + 1e-8f);
    dx *= inv; dy *= inv; dz *= inv;

    // ---- GEMM1 A-fragments: per-lane 16B k-slices direct from global ----
    const short8* hs = reinterpret_cast<const short8*>(hb + (size_t)src * 64);
    const short8* hd = reinterpret_cast<const short8*>(hb + (size_t)dst * 64);
    const short8 a0 = hs[kg];          // k =   0 + kg*8  (h_src)
    const short8 a1 = hs[4 + kg];      // k =  32 + kg*8
    const short8 a2 = hd[kg];          // k =  64 + kg*8  (h_dst)
    const short8 a3 = hd[4 + kg];      // k =  96 + kg*8
    short8 a4 = {0, 0, 0, 0, 0, 0, 0, 0};
    if (kg < 2) {                      // k = 128..143 : edge_attr
        const float4* eap = reinterpret_cast<const float4*>(ea + (size_t)eid * 16 + kg * 8);
        a4 = pack8(eap[0], eap[1]);
    } else if (kg == 2) {              // k = 144 : dist2
        a4[0] = f2bf(d2);
    }

    // ---- GEMM1: [16,160] @ [160,64] per wave ----
    f32x4 acc1[4];
    #pragma unroll
    for (int nt = 0; nt < 4; ++nt) {
        const float b = be1[r16 + nt * 16];
        acc1[nt] = {b, b, b, b};
    }
    #pragma unroll
    for (int nt = 0; nt < 4; ++nt) {
        const short* wr = W1T + (r16 + nt * 16) * 160 + kg * 8;
        acc1[nt] = __builtin_amdgcn_mfma_f32_16x16x32_bf16(
            a0, *reinterpret_cast<const short8*>(wr), acc1[nt], 0, 0, 0);
        acc1[nt] = __builtin_amdgcn_mfma_f32_16x16x32_bf16(
            a1, *reinterpret_cast<const short8*>(wr + 32), acc1[nt], 0, 0, 0);
        acc1[nt] = __builtin_amdgcn_mfma_f32_16x16x32_bf16(
            a2, *reinterpret_cast<const short8*>(wr + 64), acc1[nt], 0, 0, 0);
        acc1[nt] = __builtin_amdgcn_mfma_f32_16x16x32_bf16(
            a3, *reinterpret_cast<const short8*>(wr + 96), acc1[nt], 0, 0, 0);
        acc1[nt] = __builtin_amdgcn_mfma_f32_16x16x32_bf16(
            a4, *reinterpret_cast<const short8*>(wr + 128), acc1[nt], 0, 0, 0);
    }
    // M1 -> LDS (own wave's rows; in-order wave LDS pipe, no barrier needed)
    #pragma unroll
    for (int nt = 0; nt < 4; ++nt)
        #pragma unroll
        for (int rg = 0; rg < 4; ++rg)
            M[wave][kg * 4 + rg][r16 + nt * 16] = f2bf(fmaxf(acc1[nt][rg], 0.0f));

    // ---- GEMM2: keep f32 acc for run-aggregation ----
    const short8 a5 = *reinterpret_cast<const short8*>(&M[wave][r16][kg * 8]);
    const short8 a6 = *reinterpret_cast<const short8*>(&M[wave][r16][32 + kg * 8]);
    f32x4 acc2[4];
    #pragma unroll
    for (int nt = 0; nt < 4; ++nt) {
        const float b = be2[r16 + nt * 16];
        acc2[nt] = {b, b, b, b};
    }
    #pragma unroll
    for (int nt = 0; nt < 4; ++nt) {
        const short* wr = W2T + (r16 + nt * 16) * 64 + kg * 8;
        acc2[nt] = __builtin_amdgcn_mfma_f32_16x16x32_bf16(
            a5, *reinterpret_cast<const short8*>(wr), acc2[nt], 0, 0, 0);
        acc2[nt] = __builtin_amdgcn_mfma_f32_16x16x32_bf16(
            a6, *reinterpret_cast<const short8*>(wr + 32), acc2[nt], 0, 0, 0);
    }
    // M2 overlays M1 (reads above already issued; same-wave order guarantees)
    #pragma unroll
    for (int nt = 0; nt < 4; ++nt)
        #pragma unroll
        for (int rg = 0; rg < 4; ++rg) {
            const float v = fmaxf(acc2[nt][rg], 0.0f);
            acc2[nt][rg] = v;
            M[wave][kg * 4 + rg][r16 + nt * 16] = f2bf(v);
        }

    // ---- GEMM3: coord MLP layer 1 ----
    const short8 a7 = *reinterpret_cast<const short8*>(&M[wave][r16][kg * 8]);
    const short8 a8 = *reinterpret_cast<const short8*>(&M[wave][r16][32 + kg * 8]);
    f32x4 acc3[4];
    #pragma unroll
    for (int nt = 0; nt < 4; ++nt) {
        const float b = bc1[r16 + nt * 16];
        acc3[nt] = {b, b, b, b};
    }
    #pragma unroll
    for (int nt = 0; nt < 4; ++nt) {
        const short* wr = Wc1T + (r16 + nt * 16) * 64 + kg * 8;
        acc3[nt] = __builtin_amdgcn_mfma_f32_16x16x32_bf16(
            a7, *reinterpret_cast<const short8*>(wr), acc3[nt], 0, 0, 0);
        acc3[nt] = __builtin_amdgcn_mfma_f32_16x16x32_bf16(
            a8, *reinterpret_cast<const short8*>(wr + 32), acc3[nt], 0, 0, 0);
    }

    // ---- coef rows: cf[rg] for rows kg*4+rg (all 16 lanes of kg group) ----
    float cf[4] = {0.0f, 0.0f, 0.0f, 0.0f};
    #pragma unroll
    for (int nt = 0; nt < 4; ++nt) {
        const float wv = Wc2[r16 + nt * 16];
        #pragma unroll
        for (int rg = 0; rg < 4; ++rg)
            cf[rg] += fmaxf(acc3[nt][rg], 0.0f) * wv;
    }
    #pragma unroll
    for (int off = 1; off < 16; off <<= 1)
        #pragma unroll
        for (int rg = 0; rg < 4; ++rg)
            cf[rg] += __shfl_xor(cf[rg], off);
    const float bc2v = bc2[0];
    #pragma unroll
    for (int rg = 0; rg < 4; ++rg)
        cf[rg] = tanhf(cf[rg] + bc2v) * 0.1f;

    // cfown = coef for this lane's OWN row r16 (held by kg group r16>>2)
    const int srcl = ((r16 >> 2) << 4) + r16;
    const float c0 = __shfl(cf[0], srcl);
    const float c1 = __shfl(cf[1], srcl);
    const float c2 = __shfl(cf[2], srcl);
    const float c3 = __shfl(cf[3], srcl);
    const int rsel = r16 & 3;
    const float cfown = (rsel == 0) ? c0 : (rsel == 1) ? c1 : (rsel == 2) ? c2 : c3;

    // ---- segmented (run) reduction over sorted dst, one atomic batch/run ----
    int rstart = 0;
    while (rstart < 16) {
        const int dcur = __shfl(dkey, rstart);
        const bool inrun = (dkey == dcur) && (r16 >= rstart);
        const unsigned long long bm = __ballot(inrun);
        const int len = __popc((unsigned)bm & 0xFFFFu);
        const int rend = rstart + len;

        // agg column sums over run rows
        float s0 = 0.0f, s1 = 0.0f, s2 = 0.0f, s3 = 0.0f;
        #pragma unroll
        for (int rg = 0; rg < 4; ++rg) {
            const int row = (kg << 2) + rg;
            if (row >= rstart && row < rend) {
                s0 += acc2[0][rg]; s1 += acc2[1][rg];
                s2 += acc2[2][rg]; s3 += acc2[3][rg];
            }
        }
        s0 += __shfl_xor(s0, 16); s0 += __shfl_xor(s0, 32);
        s1 += __shfl_xor(s1, 16); s1 += __shfl_xor(s1, 32);
        s2 += __shfl_xor(s2, 16); s2 += __shfl_xor(s2, 32);
        s3 += __shfl_xor(s3, 16); s3 += __shfl_xor(s3, 32);

        // trans sums over run rows (own-row contribution per lane)
        float tx = inrun ? cfown * dx : 0.0f;
        float ty = inrun ? cfown * dy : 0.0f;
        float tz = inrun ? cfown * dz : 0.0f;
        #pragma unroll
        for (int off = 1; off < 16; off <<= 1) {
            tx += __shfl_xor(tx, off);
            ty += __shfl_xor(ty, off);
            tz += __shfl_xor(tz, off);
        }

        if (dcur >= 0) {
            // agg: 32 pk atomics spread over kg==0 lanes (2 per lane)
            #pragma unroll
            for (int nt = 0; nt < 4; ++nt) {
                const float v  = (nt == 0) ? s0 : (nt == 1) ? s1 : (nt == 2) ? s2 : s3;
                const float vp = __shfl_xor(v, 1);
                if (kg == 0 && ((r16 & 1) == (nt >> 1))) {
                    const int col0 = (r16 & ~1) + nt * 16;
                    const unsigned blo = (unsigned short)f2bf((r16 & 1) ? vp : v);
                    const unsigned bhi = (unsigned short)f2bf((r16 & 1) ? v : vp);
                    atomic_pk_add_bf16(aggb + (size_t)dcur * 64 + col0,
                                       blo | (bhi << 16));
                }
            }
            if (kg == 0 && r16 < 3) {
                const float tv = (r16 == 0) ? tx : (r16 == 1) ? ty : tz;
                unsafeAtomicAdd(&dpos[3 * dcur + r16], tv);
            }
        }
        rstart = rend;
    }
}

// ---------------------------------------------------------------------------
// Node MLP + residual + LayerNorm, MFMA version. 64 nodes/block, 4 waves.
// ---------------------------------------------------------------------------
__global__ __launch_bounds__(256) void egnn_node_mfma(
    const float* __restrict__ h, const short* __restrict__ hb,
    const short* __restrict__ aggb, const float* __restrict__ pos,
    const float* __restrict__ dpos, const short* __restrict__ WnT,
    const float* __restrict__ bn, const float* __restrict__ lng,
    const float* __restrict__ lnb,
    float* __restrict__ h_out, float* __restrict__ pos_out, int N)
{
    __shared__ short As[64][136];   // cols 0..64 = h (bf16), 64..128 = agg
    const int tid = threadIdx.x;
    const int n0  = blockIdx.x * 64;

    if (tid < 64) {
        const int n = n0 + tid;
        if (n < N) {
            #pragma unroll
            for (int c = 0; c < 3; ++c)
                pos_out[(size_t)3 * n + c] = pos[(size_t)3 * n + c] + dpos[(size_t)3 * n + c];
        }
    }

    {
        const int row = tid >> 2, part = tid & 3;
        const int n = n0 + row;
        if (n < N) {
            const short* sp = (part < 2) ? (hb + (size_t)n * 64 + (part & 1) * 32)
                                         : (aggb + (size_t)n * 64 + (part & 1) * 32);
            #pragma unroll
            for (int q = 0; q < 4; ++q)
                *reinterpret_cast<short8*>(&As[row][part * 32 + q * 8]) =
                    *reinterpret_cast<const short8*>(sp + q * 8);
        }
    }
    __syncthreads();

    const int lane = tid & 63;
    const int wave = tid >> 6;
    const int r16  = lane & 15;
    const int kg   = lane >> 4;
    const int mrow = wave * 16 + r16;

    f32x4 acc[4];
    #pragma unroll
    for (int nt = 0; nt < 4; ++nt) {
        const float b = bn[r16 + nt * 16];
        acc[nt] = {b, b, b, b};
    }
    #pragma unroll
    for (int kt = 0; kt < 4; ++kt) {
        short8 a = *reinterpret_cast<const short8*>(&As[mrow][kt * 32 + kg * 8]);
        #pragma unroll
        for (int nt = 0; nt < 4; ++nt) {
            short8 b = *reinterpret_cast<const short8*>(
                &WnT[(r16 + nt * 16) * 128 + kt * 32 + kg * 8]);
            acc[nt] = __builtin_amdgcn_mfma_f32_16x16x32_bf16(a, b, acc[nt], 0, 0, 0);
        }
    }

    float xv[4][4];
    #pragma unroll
    for (int rg = 0; rg < 4; ++rg) {
        const int n = n0 + wave * 16 + kg * 4 + rg;
        const bool ok = n < N;
        #pragma unroll
        for (int nt = 0; nt < 4; ++nt)
            xv[nt][rg] = (ok ? h[(size_t)n * 64 + r16 + nt * 16] : 0.0f)
                         + fmaxf(acc[nt][rg], 0.0f);
    }

    float g[4], bb[4];
    #pragma unroll
    for (int nt = 0; nt < 4; ++nt) { g[nt] = lng[r16 + nt * 16]; bb[nt] = lnb[r16 + nt * 16]; }

    #pragma unroll
    for (int rg = 0; rg < 4; ++rg) {
        float s = xv[0][rg] + xv[1][rg] + xv[2][rg] + xv[3][rg];
        #pragma unroll
        for (int off = 1; off < 16; off <<= 1) s += __shfl_xor(s, off);
        const float mu = s * 0.015625f;
        float q = 0.0f;
        #pragma unroll
        for (int nt = 0; nt < 4; ++nt) { const float d = xv[nt][rg] - mu; q += d * d; }
        #pragma unroll
        for (int off = 1; off < 16; off <<= 1) q += __shfl_xor(q, off);
        const float inv = rsqrtf(q * 0.015625f + 1e-5f);
        const int n = n0 + wave * 16 + kg * 4 + rg;
        if (n < N) {
            #pragma unroll
            for (int nt = 0; nt < 4; ++nt)
                h_out[(size_t)n * 64 + r16 + nt * 16] =
                    (xv[nt][rg] - mu) * inv * g[nt] + bb[nt];
        }
    }
}

extern "C" void kernel_launch(void* const* d_in, const int* in_sizes, int n_in,
                              void* d_out, int out_size, void* d_ws, size_t ws_size,
                              hipStream_t stream)
{
    const float* h   = (const float*)d_in[0];
    const float* pos = (const float*)d_in[1];
    const int*   ei  = (const int*)d_in[2];
    const float* ea  = (const float*)d_in[3];
    const float* We1 = (const float*)d_in[4];
    const float* be1 = (const float*)d_in[5];
    const float* We2 = (const float*)d_in[6];
    const float* be2 = (const float*)d_in[7];
    const float* Wc1 = (const float*)d_in[8];
    const float* bc1 = (const float*)d_in[9];
    const float* Wc2 = (const float*)d_in[10];
    const float* bc2 = (const float*)d_in[11];
    const float* Wn  = (const float*)d_in[12];
    const float* bn  = (const float*)d_in[13];
    const float* lng = (const float*)d_in[14];
    const float* lnb = (const float*)d_in[15];

    const int N = in_sizes[0] / 64;
    const int E = in_sizes[2] / 2;

    // workspace layout (zeroed region first: aggb|dpos|cnt|cursor = N*148 B)
    short* aggb   = (short*)d_ws;                       // [N,64] bf16
    float* dpos   = (float*)(aggb + (size_t)N * 64);    // [N,3]  f32
    int*   cnt    = (int*)(dpos + (size_t)3 * N);       // [N]
    int*   cursor = cnt + N;                            // [N]
    int*   startp = cursor + N;                         // [N+4] (pad for align)
    int*   eidbuf = startp + N + 4;                     // [E]
    short* W1T    = (short*)(eidbuf + E);               // [64,160]
    short* W2T    = W1T + 64 * 160;                     // [64,64]
    short* Wc1T   = W2T + 64 * 64;                      // [64,64]
    short* WnT    = Wc1T + 64 * 64;                     // [64,128]
    short* hbuf   = WnT + 64 * 128;                     // [N,64] bf16

    hipMemsetAsync(d_ws, 0, (size_t)N * 148, stream);   // aggb+dpos+cnt+cursor
    convert_weights<<<40, 256, 0, stream>>>(We1, We2, Wc1, Wn, W1T, W2T, Wc1T, WnT);
    convert_h<<<(N * 64 / 8 + 255) / 256, 256, 0, stream>>>(h, hbuf, N * 64 / 8);
    count_kernel<<<(E + 255) / 256, 256, 0, stream>>>(ei, cnt, E);
    scan_kernel<<<1, 1024, 0, stream>>>(cnt, startp, N);
    fill_kernel<<<(E + 255) / 256, 256, 0, stream>>>(ei, startp, cursor, eidbuf, E);

    float* h_out   = (float*)d_out;
    float* pos_out = h_out + (size_t)N * 64;

    egnn_edge_sorted<<<(E + 63) / 64, 256, 0, stream>>>(
        hbuf, pos, ei, ea, W1T, W2T, Wc1T, be1, be2, bc1, bc2, Wc2,
        eidbuf, aggb, dpos, E);
    egnn_node_mfma<<<(N + 63) / 64, 256, 0, stream>>>(
        h, hbuf, aggb, pos, dpos, WnT, bn, lng, lnb, h_out, pos_out, N);
}

// Round 7
// 611.003 us; speedup vs baseline: 2.1418x; 1.2099x over previous
//
#include <hip/hip_runtime.h>

using f32x4  = __attribute__((ext_vector_type(4))) float;
using short8 = __attribute__((ext_vector_type(8))) short;

__device__ inline short f2bf(float x) {
    union { float f; unsigned u; } v; v.f = x;
    unsigned r = v.u + 0x7fffu + ((v.u >> 16) & 1u);   // RNE
    return (short)(r >> 16);
}

__device__ inline short8 pack8(float4 a, float4 b) {
    short8 r;
    r[0] = f2bf(a.x); r[1] = f2bf(a.y); r[2] = f2bf(a.z); r[3] = f2bf(a.w);
    r[4] = f2bf(b.x); r[5] = f2bf(b.y); r[6] = f2bf(b.z); r[7] = f2bf(b.w);
    return r;
}

__device__ inline void atomic_pk_add_bf16(short* addr, unsigned pk) {
    asm volatile("global_atomic_pk_add_bf16 %0, %1, off"
                 :: "v"(addr), "v"(pk) : "memory");
}

// ---------------------------------------------------------------------------
// Weight prep: f32 -> bf16 transposed. Layer-1 K permuted:
// k 0..63 = h_src rows; 64..127 = h_dst rows; 128..143 = ea (orig 129..144);
// 144 = dist2 (orig 128); 145..159 = zero. WnT[64][128] for node MLP.
// ---------------------------------------------------------------------------
__global__ __launch_bounds__(256) void convert_weights(
    const float* __restrict__ We1, const float* __restrict__ We2,
    const float* __restrict__ Wc1, const float* __restrict__ Wn,
    short* __restrict__ W1T, short* __restrict__ W2T,
    short* __restrict__ Wc1T, short* __restrict__ WnT)
{
    const int i = blockIdx.x * 256 + threadIdx.x;
    if (i < 64 * 160) {
        const int n = i / 160, k = i % 160;
        float v = 0.0f;
        if (k < 128)       v = We1[k * 64 + n];
        else if (k < 144)  v = We1[(129 + k - 128) * 64 + n];
        else if (k == 144) v = We1[128 * 64 + n];
        W1T[i] = f2bf(v);
    }
    if (i < 64 * 128) {
        const int n = i / 128, k = i % 128;
        WnT[i] = f2bf(Wn[k * 64 + n]);
    }
    if (i < 64 * 64) {
        const int n = i / 64, k = i % 64;
        W2T[i]  = f2bf(We2[k * 64 + n]);
        Wc1T[i] = f2bf(Wc1[k * 64 + n]);
    }
}

__global__ __launch_bounds__(256) void convert_h(
    const float* __restrict__ h, short* __restrict__ hb, int n8)
{
    const int i = blockIdx.x * 256 + threadIdx.x;
    if (i < n8) {
        const float4* h4 = reinterpret_cast<const float4*>(h);
        reinterpret_cast<short8*>(hb)[i] = pack8(h4[2 * i], h4[2 * i + 1]);
    }
}

// ---------------------------------------------------------------------------
// CSR build: count -> 3-kernel coalesced scan -> fill(+gather src/dst/ea).
// ---------------------------------------------------------------------------
__global__ __launch_bounds__(256) void count_kernel(
    const int* __restrict__ ei, int* __restrict__ cnt, int E)
{
    const int e = blockIdx.x * 256 + threadIdx.x;
    if (e < E) atomicAdd(&cnt[ei[E + e]], 1);
}

__global__ __launch_bounds__(1024) void scan_partial(
    const int* __restrict__ cnt, int* __restrict__ bsum, int N)
{
    __shared__ int ws[16];
    const int i = blockIdx.x * 1024 + threadIdx.x;
    int v = (i < N) ? cnt[i] : 0;
    #pragma unroll
    for (int off = 1; off < 64; off <<= 1) v += __shfl_xor(v, off);
    const int lane = threadIdx.x & 63, wid = threadIdx.x >> 6;
    if (lane == 0) ws[wid] = v;
    __syncthreads();
    if (threadIdx.x == 0) {
        int s = 0;
        #pragma unroll
        for (int w = 0; w < 16; ++w) s += ws[w];
        bsum[blockIdx.x] = s;
    }
}

__global__ __launch_bounds__(1024) void scan_bsum(
    const int* __restrict__ bsum, int* __restrict__ boff, int NB)
{
    __shared__ int arr[1024];
    const int t = threadIdx.x;
    const int v = (t < NB) ? bsum[t] : 0;
    arr[t] = v;
    __syncthreads();
    for (int off = 1; off < 1024; off <<= 1) {
        const int u = (t >= off) ? arr[t - off] : 0;
        __syncthreads();
        arr[t] += u;
        __syncthreads();
    }
    if (t < NB) boff[t] = arr[t] - v;   // exclusive prefix of block sums
}

__global__ __launch_bounds__(1024) void scan_final(
    const int* __restrict__ cnt, const int* __restrict__ boff,
    int* __restrict__ start, int N, int E)
{
    __shared__ int ws[16];
    const int i = blockIdx.x * 1024 + threadIdx.x;
    const int lane = threadIdx.x & 63, wid = threadIdx.x >> 6;
    const int v = (i < N) ? cnt[i] : 0;
    int inc = v;
    #pragma unroll
    for (int off = 1; off < 64; off <<= 1) {
        const int u = __shfl_up(inc, off);
        if (lane >= off) inc += u;
    }
    if (lane == 63) ws[wid] = inc;
    __syncthreads();
    int wpre = 0;
    #pragma unroll
    for (int w = 0; w < 16; ++w) wpre += (w < wid) ? ws[w] : 0;
    if (i < N) start[i] = boff[blockIdx.x] + wpre + inc - v;
    if (i == 0) start[N] = E;
}

// fill + gather: place edge e at its dst-sorted slot, and materialize
// slot-ordered srcS/dstS/eaS(bf16) so the edge kernel reads them coalesced.
__global__ __launch_bounds__(256) void fill_gather(
    const int* __restrict__ ei, const float* __restrict__ ea,
    const int* __restrict__ start, int* __restrict__ cursor,
    int* __restrict__ srcS, int* __restrict__ dstS,
    short* __restrict__ eaS, int E)
{
    const int e = blockIdx.x * 256 + threadIdx.x;
    if (e < E) {
        const int s = ei[e];
        const int d = ei[E + e];
        const int slot = start[d] + atomicAdd(&cursor[d], 1);
        srcS[slot] = s;
        dstS[slot] = d;
        const float4* eap = reinterpret_cast<const float4*>(ea + (size_t)e * 16);
        short8* o = reinterpret_cast<short8*>(eaS + (size_t)slot * 16);
        o[0] = pack8(eap[0], eap[1]);
        o[1] = pack8(eap[2], eap[3]);
    }
}

// ---------------------------------------------------------------------------
// Edge pipeline over dst-SORTED slots: 64 slots/block, 4 independent waves
// (16 slots each), no __syncthreads. src/dst/ea read slot-coalesced (no
// random ei/ea indirection); only hb[src]/pos[src] stay random (L2/L3-hot).
// Equal-dst rows form contiguous runs -> segmented reduction, ONE atomic
// batch per run. mfma_f32_16x16x32_bf16; D: col=lane&15, row=(lane>>4)*4+reg.
// ---------------------------------------------------------------------------
__global__ __launch_bounds__(256, 6) void egnn_edge_sorted(
    const short* __restrict__ hb, const float* __restrict__ pos,
    const int* __restrict__ srcS, const int* __restrict__ dstS,
    const short* __restrict__ eaS,
    const short* __restrict__ W1T, const short* __restrict__ W2T,
    const short* __restrict__ Wc1T,
    const float* __restrict__ be1, const float* __restrict__ be2,
    const float* __restrict__ bc1, const float* __restrict__ bc2,
    const float* __restrict__ Wc2,
    short* __restrict__ aggb, float* __restrict__ dpos, int E)
{
    __shared__ short M[4][16][72];      // 9216 B, wave-private ping-pong

    const int tid  = threadIdx.x;
    const int lane = tid & 63;
    const int wave = tid >> 6;
    const int r16  = lane & 15;
    const int kg   = lane >> 4;

    const int slot  = blockIdx.x * 64 + wave * 16 + r16;
    const bool vrow = slot < E;
    const int slotc = min(slot, E - 1);
    const int src   = srcS[slotc];
    const int dst   = dstS[slotc];
    const int dkey  = vrow ? dst : -1;     // run key (-1 rows never emitted)

    // ---- geometry (per own row, kept in regs) ----
    float dx = pos[3 * dst + 0] - pos[3 * src + 0];
    float dy = pos[3 * dst + 1] - pos[3 * src + 1];
    float dz = pos[3 * dst + 2] - pos[3 * src + 2];
    const float d2 = fminf(dx * dx + dy * dy + dz * dz, 1000.0f);
    const float inv = 1.0f / sqrtf(d2 + 1e-8f);
    dx *= inv; dy *= inv; dz *= inv;

    // ---- GEMM1 A-fragments: per-lane 16B k-slices ----
    const short8* hs = reinterpret_cast<const short8*>(hb + (size_t)src * 64);
    const short8* hd = reinterpret_cast<const short8*>(hb + (size_t)dst * 64);
    const short8 a0 = hs[kg];          // k =   0 + kg*8  (h_src)
    const short8 a1 = hs[4 + kg];      // k =  32 + kg*8
    const short8 a2 = hd[kg];          // k =  64 + kg*8  (h_dst)
    const short8 a3 = hd[4 + kg];      // k =  96 + kg*8
    short8 a4 = {0, 0, 0, 0, 0, 0, 0, 0};
    if (kg < 2) {                      // k = 128..143 : edge_attr (slot-coalesced)
        a4 = *reinterpret_cast<const short8*>(eaS + (size_t)slotc * 16 + kg * 8);
    } else if (kg == 2) {              // k = 144 : dist2
        a4[0] = f2bf(d2);
    }

    // ---- GEMM1: [16,160] @ [160,64] per wave ----
    f32x4 acc1[4];
    #pragma unroll
    for (int nt = 0; nt < 4; ++nt) {
        const float b = be1[r16 + nt * 16];
        acc1[nt] = {b, b, b, b};
    }
    #pragma unroll
    for (int nt = 0; nt < 4; ++nt) {
        const short* wr = W1T + (r16 + nt * 16) * 160 + kg * 8;
        acc1[nt] = __builtin_amdgcn_mfma_f32_16x16x32_bf16(
            a0, *reinterpret_cast<const short8*>(wr), acc1[nt], 0, 0, 0);
        acc1[nt] = __builtin_amdgcn_mfma_f32_16x16x32_bf16(
            a1, *reinterpret_cast<const short8*>(wr + 32), acc1[nt], 0, 0, 0);
        acc1[nt] = __builtin_amdgcn_mfma_f32_16x16x32_bf16(
            a2, *reinterpret_cast<const short8*>(wr + 64), acc1[nt], 0, 0, 0);
        acc1[nt] = __builtin_amdgcn_mfma_f32_16x16x32_bf16(
            a3, *reinterpret_cast<const short8*>(wr + 96), acc1[nt], 0, 0, 0);
        acc1[nt] = __builtin_amdgcn_mfma_f32_16x16x32_bf16(
            a4, *reinterpret_cast<const short8*>(wr + 128), acc1[nt], 0, 0, 0);
    }
    // M1 -> LDS (own wave's rows; in-order wave LDS pipe, no barrier needed)
    #pragma unroll
    for (int nt = 0; nt < 4; ++nt)
        #pragma unroll
        for (int rg = 0; rg < 4; ++rg)
            M[wave][kg * 4 + rg][r16 + nt * 16] = f2bf(fmaxf(acc1[nt][rg], 0.0f));

    // ---- GEMM2: keep f32 acc for run-aggregation ----
    const short8 a5 = *reinterpret_cast<const short8*>(&M[wave][r16][kg * 8]);
    const short8 a6 = *reinterpret_cast<const short8*>(&M[wave][r16][32 + kg * 8]);
    f32x4 acc2[4];
    #pragma unroll
    for (int nt = 0; nt < 4; ++nt) {
        const float b = be2[r16 + nt * 16];
        acc2[nt] = {b, b, b, b};
    }
    #pragma unroll
    for (int nt = 0; nt < 4; ++nt) {
        const short* wr = W2T + (r16 + nt * 16) * 64 + kg * 8;
        acc2[nt] = __builtin_amdgcn_mfma_f32_16x16x32_bf16(
            a5, *reinterpret_cast<const short8*>(wr), acc2[nt], 0, 0, 0);
        acc2[nt] = __builtin_amdgcn_mfma_f32_16x16x32_bf16(
            a6, *reinterpret_cast<const short8*>(wr + 32), acc2[nt], 0, 0, 0);
    }
    // M2 overlays M1 (reads above already issued; same-wave order guarantees)
    #pragma unroll
    for (int nt = 0; nt < 4; ++nt)
        #pragma unroll
        for (int rg = 0; rg < 4; ++rg) {
            const float v = fmaxf(acc2[nt][rg], 0.0f);
            acc2[nt][rg] = v;
            M[wave][kg * 4 + rg][r16 + nt * 16] = f2bf(v);
        }

    // ---- GEMM3: coord MLP layer 1 ----
    const short8 a7 = *reinterpret_cast<const short8*>(&M[wave][r16][kg * 8]);
    const short8 a8 = *reinterpret_cast<const short8*>(&M[wave][r16][32 + kg * 8]);
    f32x4 acc3[4];
    #pragma unroll
    for (int nt = 0; nt < 4; ++nt) {
        const float b = bc1[r16 + nt * 16];
        acc3[nt] = {b, b, b, b};
    }
    #pragma unroll
    for (int nt = 0; nt < 4; ++nt) {
        const short* wr = Wc1T + (r16 + nt * 16) * 64 + kg * 8;
        acc3[nt] = __builtin_amdgcn_mfma_f32_16x16x32_bf16(
            a7, *reinterpret_cast<const short8*>(wr), acc3[nt], 0, 0, 0);
        acc3[nt] = __builtin_amdgcn_mfma_f32_16x16x32_bf16(
            a8, *reinterpret_cast<const short8*>(wr + 32), acc3[nt], 0, 0, 0);
    }

    // ---- coef rows: cf[rg] for rows kg*4+rg ----
    float cf[4] = {0.0f, 0.0f, 0.0f, 0.0f};
    #pragma unroll
    for (int nt = 0; nt < 4; ++nt) {
        const float wv = Wc2[r16 + nt * 16];
        #pragma unroll
        for (int rg = 0; rg < 4; ++rg)
            cf[rg] += fmaxf(acc3[nt][rg], 0.0f) * wv;
    }
    #pragma unroll
    for (int off = 1; off < 16; off <<= 1)
        #pragma unroll
        for (int rg = 0; rg < 4; ++rg)
            cf[rg] += __shfl_xor(cf[rg], off);
    const float bc2v = bc2[0];
    #pragma unroll
    for (int rg = 0; rg < 4; ++rg)
        cf[rg] = tanhf(cf[rg] + bc2v) * 0.1f;

    // cfown = coef for this lane's OWN row r16 (held by kg group r16>>2)
    const int srcl = ((r16 >> 2) << 4) + r16;
    const float c0 = __shfl(cf[0], srcl);
    const float c1 = __shfl(cf[1], srcl);
    const float c2 = __shfl(cf[2], srcl);
    const float c3 = __shfl(cf[3], srcl);
    const int rsel = r16 & 3;
    const float cfown = (rsel == 0) ? c0 : (rsel == 1) ? c1 : (rsel == 2) ? c2 : c3;

    // ---- segmented (run) reduction over sorted dst, one atomic batch/run ----
    int rstart = 0;
    while (rstart < 16) {
        const int dcur = __shfl(dkey, rstart);
        const bool inrun = (dkey == dcur) && (r16 >= rstart);
        const unsigned long long bm = __ballot(inrun);
        const int len = __popc((unsigned)bm & 0xFFFFu);
        const int rend = rstart + len;

        float s0 = 0.0f, s1 = 0.0f, s2 = 0.0f, s3 = 0.0f;
        #pragma unroll
        for (int rg = 0; rg < 4; ++rg) {
            const int row = (kg << 2) + rg;
            if (row >= rstart && row < rend) {
                s0 += acc2[0][rg]; s1 += acc2[1][rg];
                s2 += acc2[2][rg]; s3 += acc2[3][rg];
            }
        }
        s0 += __shfl_xor(s0, 16); s0 += __shfl_xor(s0, 32);
        s1 += __shfl_xor(s1, 16); s1 += __shfl_xor(s1, 32);
        s2 += __shfl_xor(s2, 16); s2 += __shfl_xor(s2, 32);
        s3 += __shfl_xor(s3, 16); s3 += __shfl_xor(s3, 32);

        float tx = inrun ? cfown * dx : 0.0f;
        float ty = inrun ? cfown * dy : 0.0f;
        float tz = inrun ? cfown * dz : 0.0f;
        #pragma unroll
        for (int off = 1; off < 16; off <<= 1) {
            tx += __shfl_xor(tx, off);
            ty += __shfl_xor(ty, off);
            tz += __shfl_xor(tz, off);
        }

        if (dcur >= 0) {
            #pragma unroll
            for (int nt = 0; nt < 4; ++nt) {
                const float v  = (nt == 0) ? s0 : (nt == 1) ? s1 : (nt == 2) ? s2 : s3;
                const float vp = __shfl_xor(v, 1);
                if (kg == 0 && ((r16 & 1) == (nt >> 1))) {
                    const int col0 = (r16 & ~1) + nt * 16;
                    const unsigned blo = (unsigned short)f2bf((r16 & 1) ? vp : v);
                    const unsigned bhi = (unsigned short)f2bf((r16 & 1) ? v : vp);
                    atomic_pk_add_bf16(aggb + (size_t)dcur * 64 + col0,
                                       blo | (bhi << 16));
                }
            }
            if (kg == 0 && r16 < 3) {
                const float tv = (r16 == 0) ? tx : (r16 == 1) ? ty : tz;
                unsafeAtomicAdd(&dpos[3 * dcur + r16], tv);
            }
        }
        rstart = rend;
    }
}

// ---------------------------------------------------------------------------
// Node MLP + residual + LayerNorm, MFMA version. 64 nodes/block, 4 waves.
// ---------------------------------------------------------------------------
__global__ __launch_bounds__(256) void egnn_node_mfma(
    const float* __restrict__ h, const short* __restrict__ hb,
    const short* __restrict__ aggb, const float* __restrict__ pos,
    const float* __restrict__ dpos, const short* __restrict__ WnT,
    const float* __restrict__ bn, const float* __restrict__ lng,
    const float* __restrict__ lnb,
    float* __restrict__ h_out, float* __restrict__ pos_out, int N)
{
    __shared__ short As[64][136];   // cols 0..64 = h (bf16), 64..128 = agg
    const int tid = threadIdx.x;
    const int n0  = blockIdx.x * 64;

    if (tid < 64) {
        const int n = n0 + tid;
        if (n < N) {
            #pragma unroll
            for (int c = 0; c < 3; ++c)
                pos_out[(size_t)3 * n + c] = pos[(size_t)3 * n + c] + dpos[(size_t)3 * n + c];
        }
    }

    {
        const int row = tid >> 2, part = tid & 3;
        const int n = n0 + row;
        if (n < N) {
            const short* sp = (part < 2) ? (hb + (size_t)n * 64 + (part & 1) * 32)
                                         : (aggb + (size_t)n * 64 + (part & 1) * 32);
            #pragma unroll
            for (int q = 0; q < 4; ++q)
                *reinterpret_cast<short8*>(&As[row][part * 32 + q * 8]) =
                    *reinterpret_cast<const short8*>(sp + q * 8);
        }
    }
    __syncthreads();

    const int lane = tid & 63;
    const int wave = tid >> 6;
    const int r16  = lane & 15;
    const int kg   = lane >> 4;
    const int mrow = wave * 16 + r16;

    f32x4 acc[4];
    #pragma unroll
    for (int nt = 0; nt < 4; ++nt) {
        const float b = bn[r16 + nt * 16];
        acc[nt] = {b, b, b, b};
    }
    #pragma unroll
    for (int kt = 0; kt < 4; ++kt) {
        short8 a = *reinterpret_cast<const short8*>(&As[mrow][kt * 32 + kg * 8]);
        #pragma unroll
        for (int nt = 0; nt < 4; ++nt) {
            short8 b = *reinterpret_cast<const short8*>(
                &WnT[(r16 + nt * 16) * 128 + kt * 32 + kg * 8]);
            acc[nt] = __builtin_amdgcn_mfma_f32_16x16x32_bf16(a, b, acc[nt], 0, 0, 0);
        }
    }

    float xv[4][4];
    #pragma unroll
    for (int rg = 0; rg < 4; ++rg) {
        const int n = n0 + wave * 16 + kg * 4 + rg;
        const bool ok = n < N;
        #pragma unroll
        for (int nt = 0; nt < 4; ++nt)
            xv[nt][rg] = (ok ? h[(size_t)n * 64 + r16 + nt * 16] : 0.0f)
                         + fmaxf(acc[nt][rg], 0.0f);
    }

    float g[4], bb[4];
    #pragma unroll
    for (int nt = 0; nt < 4; ++nt) { g[nt] = lng[r16 + nt * 16]; bb[nt] = lnb[r16 + nt * 16]; }

    #pragma unroll
    for (int rg = 0; rg < 4; ++rg) {
        float s = xv[0][rg] + xv[1][rg] + xv[2][rg] + xv[3][rg];
        #pragma unroll
        for (int off = 1; off < 16; off <<= 1) s += __shfl_xor(s, off);
        const float mu = s * 0.015625f;
        float q = 0.0f;
        #pragma unroll
        for (int nt = 0; nt < 4; ++nt) { const float d = xv[nt][rg] - mu; q += d * d; }
        #pragma unroll
        for (int off = 1; off < 16; off <<= 1) q += __shfl_xor(q, off);
        const float inv = rsqrtf(q * 0.015625f + 1e-5f);
        const int n = n0 + wave * 16 + kg * 4 + rg;
        if (n < N) {
            #pragma unroll
            for (int nt = 0; nt < 4; ++nt)
                h_out[(size_t)n * 64 + r16 + nt * 16] =
                    (xv[nt][rg] - mu) * inv * g[nt] + bb[nt];
        }
    }
}

extern "C" void kernel_launch(void* const* d_in, const int* in_sizes, int n_in,
                              void* d_out, int out_size, void* d_ws, size_t ws_size,
                              hipStream_t stream)
{
    const float* h   = (const float*)d_in[0];
    const float* pos = (const float*)d_in[1];
    const int*   ei  = (const int*)d_in[2];
    const float* ea  = (const float*)d_in[3];
    const float* We1 = (const float*)d_in[4];
    const float* be1 = (const float*)d_in[5];
    const float* We2 = (const float*)d_in[6];
    const float* be2 = (const float*)d_in[7];
    const float* Wc1 = (const float*)d_in[8];
    const float* bc1 = (const float*)d_in[9];
    const float* Wc2 = (const float*)d_in[10];
    const float* bc2 = (const float*)d_in[11];
    const float* Wn  = (const float*)d_in[12];
    const float* bn  = (const float*)d_in[13];
    const float* lng = (const float*)d_in[14];
    const float* lnb = (const float*)d_in[15];

    const int N = in_sizes[0] / 64;
    const int E = in_sizes[2] / 2;
    const int NB = (N + 1023) / 1024;

    // workspace layout (16B-aligned short arrays first)
    short* aggb = (short*)d_ws;                         // [N,64] bf16
    short* hbuf = aggb + (size_t)N * 64;                // [N,64] bf16
    short* eaS  = hbuf + (size_t)N * 64;                // [E,16] bf16 (sorted)
    short* W1T  = eaS + (size_t)E * 16;                 // [64,160]
    short* W2T  = W1T + 64 * 160;                       // [64,64]
    short* Wc1T = W2T + 64 * 64;                        // [64,64]
    short* WnT  = Wc1T + 64 * 64;                       // [64,128]
    float* dpos = (float*)(WnT + 64 * 128);             // [N,3]  f32
    int* cnt    = (int*)(dpos + (size_t)3 * N);         // [N]
    int* cursor = cnt + N;                              // [N]
    int* startp = cursor + N;                           // [N+1]
    int* bsum   = startp + N + 1;                       // [NB<=1024]
    int* boff   = bsum + 1024;                          // [NB]
    int* srcS   = boff + 1024;                          // [E] (sorted)
    int* dstS   = srcS + E;                             // [E] (sorted)

    hipMemsetAsync(aggb, 0, (size_t)N * 128, stream);           // aggb
    hipMemsetAsync(dpos, 0, (size_t)N * 20, stream);            // dpos+cnt+cursor
    convert_weights<<<40, 256, 0, stream>>>(We1, We2, Wc1, Wn, W1T, W2T, Wc1T, WnT);
    convert_h<<<(N * 64 / 8 + 255) / 256, 256, 0, stream>>>(h, hbuf, N * 64 / 8);
    count_kernel<<<(E + 255) / 256, 256, 0, stream>>>(ei, cnt, E);
    scan_partial<<<NB, 1024, 0, stream>>>(cnt, bsum, N);
    scan_bsum<<<1, 1024, 0, stream>>>(bsum, boff, NB);
    scan_final<<<NB, 1024, 0, stream>>>(cnt, boff, startp, N, E);
    fill_gather<<<(E + 255) / 256, 256, 0, stream>>>(
        ei, ea, startp, cursor, srcS, dstS, eaS, E);

    float* h_out   = (float*)d_out;
    float* pos_out = h_out + (size_t)N * 64;

    egnn_edge_sorted<<<(E + 63) / 64, 256, 0, stream>>>(
        hbuf, pos, srcS, dstS, eaS, W1T, W2T, Wc1T,
        be1, be2, bc1, bc2, Wc2, aggb, dpos, E);
    egnn_node_mfma<<<(N + 63) / 64, 256, 0, stream>>>(
        h, hbuf, aggb, pos, dpos, WnT, bn, lng, lnb, h_out, pos_out, N);
}